// Round 7
// baseline (1453.409 us; speedup 1.0000x reference)
//
#include <hip/hip_runtime.h>
#include <hip/hip_bf16.h>
#include <stdint.h>

#define DM 1024            // d_model
#define DN 4096            // d_neuron
#define BB 2               // batch
#define TT 4096            // seq
#define MR (BB*TT)         // 8192 total GEMM rows
#define TC 512             // time chunk
#define NTC (TT/TC)        // 8 time chunks
#define CR (BB*TC)         // 1024 rows per chunk
#define CN ((size_t)CR*DN) // per-chunk activation elems (4,194,304)
#define SCH 16             // scan sub-chunk (32 tg x 16 = TC)

typedef unsigned short u16;
typedef __attribute__((ext_vector_type(8))) short bf16x8;
typedef __attribute__((ext_vector_type(4))) float f32x4;

__device__ __forceinline__ float bf2f(u16 u) {
    unsigned int x = ((unsigned int)u) << 16; float f; __builtin_memcpy(&f, &x, 4); return f;
}
__device__ __forceinline__ u16 f2bf(float f) {
    __hip_bfloat16 h = __float2bfloat16(f); u16 u; __builtin_memcpy(&u, &h, 2); return u;
}
// fast tanh: 1 - 2/(exp(2x)+1); exact at +-inf, abs err ~1e-7
__device__ __forceinline__ float tanh_fast(float x) {
    float e = __expf(2.f * x);
    return 1.f - 2.f / (e + 1.f);
}
// A&S 7.1.26 erf poly, max abs err 1.5e-7
__device__ __forceinline__ float erf_fast(float x) {
    float ax = fabsf(x);
    float t = 1.f / (1.f + 0.3275911f * ax);
    float y = t * (0.254829592f + t * (-0.284496736f + t * (1.421413741f +
              t * (-1.453152027f + t * 1.061405429f))));
    float r = 1.f - y * __expf(-ax * ax);
    return copysignf(r, x);
}
// async global->LDS, 16 B per lane (dest = wave-uniform base + lane*16)
__device__ __forceinline__ void async16(const void* g, void* l) {
    __builtin_amdgcn_global_load_lds(
        (const __attribute__((address_space(1))) void*)(uintptr_t)g,
        (__attribute__((address_space(3))) void*)(uint32_t)(uintptr_t)l,
        16, 0, 0);
}

// ---------------- fused fp32 -> bf16 conversion: x + 4 proj weights + W_out ----------------
__global__ void cvt6_kernel(const float4* __restrict__ x,
                            const float4* __restrict__ w0, const float4* __restrict__ w1,
                            const float4* __restrict__ w2, const float4* __restrict__ w3,
                            const float4* __restrict__ wo,
                            ushort4* __restrict__ xb, ushort4* __restrict__ w4b,
                            ushort4* __restrict__ woutb)
{
    const int XQ = (MR * DM) / 4;        // 2,097,152
    const int WQ = (DN * DM) / 4;        // 1,048,576 = 2^20
    int i = blockIdx.x * 256 + threadIdx.x;
    const float4* s; ushort4* d;
    if (i < XQ) { s = x + i; d = xb + i; }
    else {
        int j = i - XQ;
        int seg = j >> 20;
        int off = j & (WQ - 1);
        if (seg < 4) {
            const float4* ws = (seg == 0) ? w0 : (seg == 1) ? w1 : (seg == 2) ? w2 : w3;
            s = ws + off; d = w4b + j;
        } else {
            s = wo + off; d = woutb + off;
        }
    }
    float4 v = *s;
    ushort4 o; o.x = f2bf(v.x); o.y = f2bf(v.y); o.z = f2bf(v.z); o.w = f2bf(v.w);
    *d = o;
}

#define BM 128
#define BN 128
#define BK 64

// ---------------- 4 input projections, 256x128 per block (two m-tiles share B) ----------------
// Grid 512 = 2 blocks/CU resident. XCD x owns (n,w) pairs [x*16, x*16+16) -> per-XCD W
// working set 4MB = L2 (verified round 5). Per block: 2x per-block FLOP vs round 6 ->
// per-block overhead O amortized; 12 ds_read_b128 feed 32 MFMA (was 8:16).
__global__ __launch_bounds__(256, 2) void gemm4_kernel(
    const u16* __restrict__ Xb,             // bf16 [8192][1024]
    const u16* __restrict__ W4b,            // bf16 [4][4096][1024]
    u16* __restrict__ raw_o, u16* __restrict__ sig_o,
    u16* __restrict__ modp_o, u16* __restrict__ omd_o,
    const float* __restrict__ A_log, const float* __restrict__ b_delta, int ci)
{
    const int bid = blockIdx.x;              // 0..511
    const int xcd = bid & 7;
    const int g = bid >> 3;                  // 0..63
    const int m_pair = g & 3;                // 4 pairs of m-tiles (256 rows each)
    const int pair = xcd * 16 + (g >> 2);    // 0..127 = 32 n-tiles x 4 w
    const int n_idx = pair & 31;
    const int w = pair >> 5;

    const u16* Wp = W4b + (size_t)w * DN * DM;
    u16* Op = (w == 0) ? raw_o : (w == 1) ? sig_o : (w == 2) ? modp_o : omd_o;
    const int n0 = n_idx * BN;
    const int m0 = m_pair * 256;             // two tiles: m0, m0+128

    alignas(16) __shared__ u16 As[2 * BM * BK];   // 32 KB (two m-tiles)
    alignas(16) __shared__ u16 Bs[BN * BK];       // 16 KB

    const int tid = threadIdx.x;
    const int lane = tid & 63;
    const int wave = tid >> 6;
    const int wm = (wave >> 1) * 64;
    const int wn = (wave & 1) * 64;
    const int l16 = lane & 15;
    const int quad = lane >> 4;
    const int sr8 = lane >> 3;
    const int cl = lane & 7;

    const f32x4 z4 = {0.f, 0.f, 0.f, 0.f};
    f32x4 acc[2][4][4];                      // [m-half][i][j] -> 128 AGPRs
#pragma unroll
    for (int h = 0; h < 2; h++)
#pragma unroll
        for (int i = 0; i < 4; i++)
#pragma unroll
            for (int j = 0; j < 4; j++) acc[h][i][j] = z4;

    for (int kt = 0; kt < DM; kt += BK) {
        __syncthreads();
#pragma unroll
        for (int it = 0; it < 4; ++it) {
            const int r = wave * 32 + it * 8 + sr8;       // 0..127
            const int cg = cl ^ (r & 7);                  // XOR-8 swizzle
            async16(Wp + (size_t)(n0 + r) * DM + kt + cg * 8,
                    Bs + (wave * 32 + it * 8) * BK);
            // A low half (rows m0+r) and high half (rows m0+128+r)
            const int lr0 = m0 + r;
            const int xr0 = ((lr0 >> 9) << 12) + ci * TC + (lr0 & (TC - 1));
            async16(Xb + (size_t)xr0 * DM + kt + cg * 8,
                    As + (wave * 32 + it * 8) * BK);
            const int lr1 = m0 + 128 + r;
            const int xr1 = ((lr1 >> 9) << 12) + ci * TC + (lr1 & (TC - 1));
            async16(Xb + (size_t)xr1 * DM + kt + cg * 8,
                    As + (BM + wave * 32 + it * 8) * BK);
        }
        __syncthreads();
#pragma unroll
        for (int ks = 0; ks < BK; ks += 32) {
            bf16x8 af[2][4], bfr[4];
#pragma unroll
            for (int i = 0; i < 4; i++) {
                const int r = wm + i * 16 + l16;
                const int ch = ((ks >> 3) + quad) ^ (r & 7);
                af[0][i] = *(const bf16x8*)(As + r * BK + ch * 8);
                af[1][i] = *(const bf16x8*)(As + (BM + r) * BK + ch * 8);
            }
#pragma unroll
            for (int j = 0; j < 4; j++) {
                const int r = wn + j * 16 + l16;
                const int ch = ((ks >> 3) + quad) ^ (r & 7);
                bfr[j] = *(const bf16x8*)(Bs + r * BK + ch * 8);
            }
#pragma unroll
            for (int h = 0; h < 2; h++)
#pragma unroll
                for (int i = 0; i < 4; i++)
#pragma unroll
                    for (int j = 0; j < 4; j++)
                        acc[h][i][j] = __builtin_amdgcn_mfma_f32_16x16x32_bf16(
                            af[h][i], bfr[j], acc[h][i][j], 0, 0, 0);
        }
    }

    // hoisted per-column params for w=3 (n depends only on j)
    float Aj[4], bdj[4];
    if (w == 3) {
#pragma unroll
        for (int j = 0; j < 4; j++) {
            int n = n0 + wn + j * 16 + l16;
            Aj[j] = __expf(A_log[n]);
            bdj[j] = b_delta[n];
        }
    }

    // epilogue: C/D layout col=lane&15, row=quad*4+reg (m89-verified)
#pragma unroll
    for (int h = 0; h < 2; h++) {
#pragma unroll
        for (int i = 0; i < 4; i++) {
#pragma unroll
            for (int j = 0; j < 4; j++) {
                int n = n0 + wn + j * 16 + l16;
#pragma unroll
                for (int r = 0; r < 4; r++) {
                    int m = m0 + h * 128 + wm + i * 16 + quad * 4 + r;
                    float z = acc[h][i][j][r];
                    float o;
                    if (w == 0) {
                        o = z;                                    // raw
                    } else if (w == 1) {
                        o = 1.f / (1.f + __expf(-z));             // sigmoid gate
                    } else if (w == 2) {
                        o = 1.f + tanh_fast(z);                   // 1 + mod
                    } else {
                        float v = z + bdj[j];                     // softplus, stable
                        float sp = fmaxf(v, 0.f) + __logf(1.f + __expf(-fabsf(v)));
                        o = 1.f - __expf(-Aj[j] * sp);            // 1 - decay
                    }
                    Op[(size_t)m * DN + n] = f2bf(o);
                }
            }
        }
    }
}

// ---------------- output GEMM: out[m][dm] = sum_k Z[m][k]*W_out[dm][k], K=4096 ----------------
__global__ __launch_bounds__(256, 4) void gemm_out_kernel(
    const u16* __restrict__ Zb, const u16* __restrict__ Wob, float* __restrict__ Out)
{
    const int bid = blockIdx.x;              // 0..511
    const int xcd = bid & 7;
    const int g = bid >> 3;                  // 0..63
    const int n_idx = g & 7;
    const int m_idx = xcd * 8 + (g >> 3);    // 0..63
    const int n0 = n_idx * BN;
    const int m0 = m_idx * BM;

    alignas(16) __shared__ u16 As[BM * BK];
    alignas(16) __shared__ u16 Bs[BN * BK];

    const int tid = threadIdx.x;
    const int lane = tid & 63;
    const int wave = tid >> 6;
    const int wm = (wave >> 1) * 64;
    const int wn = (wave & 1) * 64;
    const int l16 = lane & 15;
    const int quad = lane >> 4;
    const int sr8 = lane >> 3;
    const int cl = lane & 7;

    const f32x4 z4 = {0.f, 0.f, 0.f, 0.f};
    f32x4 acc[4][4];
#pragma unroll
    for (int i = 0; i < 4; i++)
#pragma unroll
        for (int j = 0; j < 4; j++) acc[i][j] = z4;

    for (int kt = 0; kt < DN; kt += BK) {
        __syncthreads();
#pragma unroll
        for (int it = 0; it < 4; ++it) {
            const int r = wave * 32 + it * 8 + sr8;
            const int cg = cl ^ (r & 7);
            async16(Zb + (size_t)(m0 + r) * DN + kt + cg * 8,
                    As + (wave * 32 + it * 8) * BK);
            async16(Wob + (size_t)(n0 + r) * DN + kt + cg * 8,
                    Bs + (wave * 32 + it * 8) * BK);
        }
        __syncthreads();
#pragma unroll
        for (int ks = 0; ks < BK; ks += 32) {
            bf16x8 af[4], bfr[4];
#pragma unroll
            for (int i = 0; i < 4; i++) {
                const int r = wm + i * 16 + l16;
                const int ch = ((ks >> 3) + quad) ^ (r & 7);
                af[i] = *(const bf16x8*)(As + r * BK + ch * 8);
            }
#pragma unroll
            for (int j = 0; j < 4; j++) {
                const int r = wn + j * 16 + l16;
                const int ch = ((ks >> 3) + quad) ^ (r & 7);
                bfr[j] = *(const bf16x8*)(Bs + r * BK + ch * 8);
            }
#pragma unroll
            for (int i = 0; i < 4; i++)
#pragma unroll
                for (int j = 0; j < 4; j++)
                    acc[i][j] = __builtin_amdgcn_mfma_f32_16x16x32_bf16(af[i], bfr[j], acc[i][j], 0, 0, 0);
        }
    }

#pragma unroll
    for (int i = 0; i < 4; i++)
#pragma unroll
        for (int j = 0; j < 4; j++) {
            int n = n0 + wn + j * 16 + l16;
#pragma unroll
            for (int r = 0; r < 4; r++) {
                int m = m0 + wm + i * 16 + quad * 4 + r;
                Out[(size_t)m * DM + n] = acc[i][j][r];
            }
        }
}

// ---------------- single-kernel hierarchical scan for one time chunk ----------------
__global__ __launch_bounds__(1024) void scan_fused(
    const u16* __restrict__ omd_a, const u16* __restrict__ sig_a,
    const u16* __restrict__ raw_a, const u16* __restrict__ modp_a,
    float* __restrict__ state_cur, const float* __restrict__ sw_logit,
    u16* __restrict__ Z, float* __restrict__ fs_out, int ci_t)
{
    __shared__ float Ds[32][32];
    __shared__ float Ss[32][32];
    __shared__ float Is[32][32];

    const int tid = threadIdx.x;
    const int nl = tid & 31;
    const int tg = tid >> 5;
    const int bx = blockIdx.x;               // BB * (DN/32) = 256 blocks
    const int nsl = bx & 127;
    const int b = bx >> 7;
    const int n = nsl * 32 + nl;

    const size_t base = ((size_t)(b * TC + tg * SCH)) * DN + n;   // chunk-local rows

    // phase 1: sub-chunk summary
    float D = 1.f, s = 0.f;
#pragma unroll
    for (int t = 0; t < SCH; t++) {
        size_t idx = base + (size_t)t * DN;
        float omd = bf2f(omd_a[idx]);
        float sg = bf2f(sig_a[idx]);
        float rw = bf2f(raw_a[idx]);
        float d = 1.f - omd;
        float u = omd * sg * tanh_fast(rw);
        D *= d;
        s = d * s + u;
    }
    Ds[tg][nl] = D;
    Ss[tg][nl] = s;
    __syncthreads();

    // prefix combine: tg==0 threads (one per neuron) walk the 32 summaries
    if (tg == 0) {
        float si = state_cur[b * DN + n];
        Is[0][nl] = si;
        for (int c = 0; c < 31; c++) {
            si = Ds[c][nl] * si + Ss[c][nl];
            Is[c + 1][nl] = si;
        }
    }
    __syncthreads();

    // phase 2: re-scan with true init, emit Z
    float s2 = Is[tg][nl];
    const float sw = 1.f / (1.f + __expf(-sw_logit[n]));
    const float osw = 1.f - sw;
    const size_t gbase = ((size_t)(b * TT + ci_t * TC + tg * SCH)) * DN + n;
#pragma unroll
    for (int t = 0; t < SCH; t++) {
        size_t li = base + (size_t)t * DN;
        float omd = bf2f(omd_a[li]);
        float sg = bf2f(sig_a[li]);
        float rw = bf2f(raw_a[li]);
        float mp = bf2f(modp_a[li]);
        float d = 1.f - omd;
        float u = omd * sg * tanh_fast(rw);
        s2 = d * s2 + u;
        float g2 = 0.5f * rw * (1.f + erf_fast(rw * 0.70710678f));  // exact gelu
        Z[gbase + (size_t)t * DN] = f2bf(mp * (osw * g2 + sw * s2));
    }
    if (tg == 31) {
        state_cur[b * DN + n] = s2;                 // carry to next chunk
        if (ci_t == NTC - 1) fs_out[b * DN + n] = s2;  // final_state output
    }
}

// ---------------- host launcher ----------------
extern "C" void kernel_launch(void* const* d_in, const int* in_sizes, int n_in,
                              void* d_out, int out_size, void* d_ws, size_t ws_size,
                              hipStream_t stream)
{
    const float* x = (const float*)d_in[0];
    const float* state = (const float*)d_in[1];
    const float* W_main = (const float*)d_in[2];
    const float* W_gate = (const float*)d_in[3];
    const float* W_mod = (const float*)d_in[4];
    const float* W_out = (const float*)d_in[5];
    const float* W_delta = (const float*)d_in[6];
    const float* b_delta = (const float*)d_in[7];
    const float* A_log = (const float*)d_in[8];
    const float* sw_logit = (const float*)d_in[9];

    float* out = (float*)d_out;                       // [B,T,Dm] fp32
    float* fs_out = out + (size_t)MR * DM;            // final_state [B,Dn]

    const size_t NM = (size_t)MR * DN;
    u16* Zb = (u16*)d_ws;                             // 67.11 MB
    u16* raw_c = Zb + NM;                             // 4 x 8.39 MB
    u16* sig_c = raw_c + CN;
    u16* modp_c = sig_c + CN;
    u16* omd_c = modp_c + CN;
    u16* W4b = omd_c + CN;                            // 33.55 MB
    u16* xb = W4b + (size_t)4 * DN * DM;              // 16.78 MB
    u16* woutb = xb + (size_t)MR * DM;                // 8.39 MB
    float* state_cur = (float*)(woutb + (size_t)DM * DN); // 32 KB
    // total = 159,416,320 B  (< 160,202,752 proven available)

    hipMemcpyAsync(state_cur, state, (size_t)BB * DN * sizeof(float),
                   hipMemcpyDeviceToDevice, stream);

    // one fused conversion launch: x + 4 projection weights + W_out
    {
        const int total4 = (MR * DM) / 4 + 5 * ((DN * DM) / 4);   // 7,340,032
        cvt6_kernel<<<total4 / 256, 256, 0, stream>>>(
            (const float4*)x, (const float4*)W_main, (const float4*)W_gate,
            (const float4*)W_mod, (const float4*)W_delta, (const float4*)W_out,
            (ushort4*)xb, (ushort4*)W4b, (ushort4*)woutb);
    }

    for (int ci = 0; ci < NTC; ci++) {
        gemm4_kernel<<<512, 256, 0, stream>>>(xb, W4b, raw_c, sig_c, modp_c, omd_c,
                                              A_log, b_delta, ci);
        scan_fused<<<BB * (DN / 32), 1024, 0, stream>>>(omd_c, sig_c, raw_c, modp_c,
                                                        state_cur, sw_logit,
                                                        Zb, fs_out, ci);
    }

    gemm_out_kernel<<<512, 256, 0, stream>>>(Zb, woutb, out);
}

// Round 8
// 721.324 us; speedup vs baseline: 2.0149x; 2.0149x over previous
//
#include <hip/hip_runtime.h>
#include <hip/hip_bf16.h>
#include <stdint.h>

#define DM 1024            // d_model
#define DN 4096            // d_neuron
#define BB 2               // batch
#define TT 4096            // seq
#define MR (BB*TT)         // 8192 total GEMM rows
#define TC 512             // time chunk
#define NTC (TT/TC)        // 8 time chunks
#define CR (BB*TC)         // 1024 rows per chunk
#define CN ((size_t)CR*DN) // per-chunk activation elems (4,194,304)
#define SCH 16             // scan sub-chunk (32 tg x 16 = TC)

typedef unsigned short u16;
typedef __attribute__((ext_vector_type(8))) short bf16x8;
typedef __attribute__((ext_vector_type(4))) float f32x4;

__device__ __forceinline__ float bf2f(u16 u) {
    unsigned int x = ((unsigned int)u) << 16; float f; __builtin_memcpy(&f, &x, 4); return f;
}
__device__ __forceinline__ u16 f2bf(float f) {
    __hip_bfloat16 h = __float2bfloat16(f); u16 u; __builtin_memcpy(&u, &h, 2); return u;
}
// fast tanh: 1 - 2/(exp(2x)+1); exact at +-inf, abs err ~1e-7
__device__ __forceinline__ float tanh_fast(float x) {
    float e = __expf(2.f * x);
    return 1.f - 2.f / (e + 1.f);
}
// A&S 7.1.26 erf poly, max abs err 1.5e-7
__device__ __forceinline__ float erf_fast(float x) {
    float ax = fabsf(x);
    float t = 1.f / (1.f + 0.3275911f * ax);
    float y = t * (0.254829592f + t * (-0.284496736f + t * (1.421413741f +
              t * (-1.453152027f + t * 1.061405429f))));
    float r = 1.f - y * __expf(-ax * ax);
    return copysignf(r, x);
}
// async global->LDS, 16 B per lane (dest = wave-uniform base + lane*16)
__device__ __forceinline__ void async16(const void* g, void* l) {
    __builtin_amdgcn_global_load_lds(
        (const __attribute__((address_space(1))) void*)(uintptr_t)g,
        (__attribute__((address_space(3))) void*)(uint32_t)(uintptr_t)l,
        16, 0, 0);
}

// -------- fused conversion: x + 4 proj weights + W_out (fp32->bf16) + state copy --------
__global__ void cvt7_kernel(const float4* __restrict__ x,
                            const float4* __restrict__ w0, const float4* __restrict__ w1,
                            const float4* __restrict__ w2, const float4* __restrict__ w3,
                            const float4* __restrict__ wo, const float4* __restrict__ st,
                            ushort4* __restrict__ xb, ushort4* __restrict__ w4b,
                            ushort4* __restrict__ woutb, float4* __restrict__ state_cur)
{
    const int XQ = (MR * DM) / 4;        // 2,097,152
    const int WQ = (DN * DM) / 4;        // 1,048,576 = 2^20
    const int SQ = XQ + 5 * WQ;          // start of state segment
    int i = blockIdx.x * 256 + threadIdx.x;
    if (i >= SQ) {                        // state passthrough (BB*DN/4 = 2048 float4)
        int j = i - SQ;
        if (j < (BB * DN) / 4) state_cur[j] = st[j];
        return;
    }
    const float4* s; ushort4* d;
    if (i < XQ) { s = x + i; d = xb + i; }
    else {
        int j = i - XQ;
        int seg = j >> 20;
        int off = j & (WQ - 1);
        if (seg < 4) {
            const float4* ws = (seg == 0) ? w0 : (seg == 1) ? w1 : (seg == 2) ? w2 : w3;
            s = ws + off; d = w4b + j;
        } else {
            s = wo + off; d = woutb + off;
        }
    }
    float4 v = *s;
    ushort4 o; o.x = f2bf(v.x); o.y = f2bf(v.y); o.z = f2bf(v.z); o.w = f2bf(v.w);
    *d = o;
}

#define BM 128
#define BN 128
#define BK 64

// ---------------- 4 input projections for one time chunk, fused activations ----------------
// ROUND-6 VERBATIM (proven ~75 us). XCD x owns (n,w) pairs [x*16,x*16+16); 8 m-blocks per
// pair co-resident -> per-XCD W working set 4MB = L2 (FETCH verified round 5/7).
// NOTE (round-7 lesson): keep acc <= 64 AGPRs and >= 4 blocks/CU; 128-AGPR acc collapsed
// occupancy to 2 phase-locked blocks/CU and regressed 2x.
__global__ __launch_bounds__(256, 4) void gemm4_kernel(
    const u16* __restrict__ Xb,             // bf16 [8192][1024]
    const u16* __restrict__ W4b,            // bf16 [4][4096][1024]
    u16* __restrict__ raw_o, u16* __restrict__ sig_o,
    u16* __restrict__ modp_o, u16* __restrict__ omd_o,
    const float* __restrict__ A_log, const float* __restrict__ b_delta, int ci)
{
    const int bid = blockIdx.x;              // 0..1023
    const int xcd = bid & 7;
    const int g = bid >> 3;                  // 0..127
    const int m_idx = g & 7;
    const int pair = xcd * 16 + (g >> 3);    // 0..127 = 32 n-tiles x 4 w
    const int n_idx = pair & 31;
    const int w = pair >> 5;

    const u16* Wp = W4b + (size_t)w * DN * DM;
    u16* Op = (w == 0) ? raw_o : (w == 1) ? sig_o : (w == 2) ? modp_o : omd_o;
    const int n0 = n_idx * BN;
    const int m0 = m_idx * BM;

    alignas(16) __shared__ u16 As[BM * BK];
    alignas(16) __shared__ u16 Bs[BN * BK];

    const int tid = threadIdx.x;
    const int lane = tid & 63;
    const int wave = tid >> 6;
    const int wm = (wave >> 1) * 64;
    const int wn = (wave & 1) * 64;
    const int l16 = lane & 15;
    const int quad = lane >> 4;
    const int sr8 = lane >> 3;
    const int cl = lane & 7;

    const f32x4 z4 = {0.f, 0.f, 0.f, 0.f};
    f32x4 acc[4][4];
#pragma unroll
    for (int i = 0; i < 4; i++)
#pragma unroll
        for (int j = 0; j < 4; j++) acc[i][j] = z4;

    for (int kt = 0; kt < DM; kt += BK) {
        __syncthreads();
#pragma unroll
        for (int it = 0; it < 4; ++it) {
            const int r = wave * 32 + it * 8 + sr8;
            const int cg = cl ^ (r & 7);                  // XOR-8 swizzle
            async16(Wp + (size_t)(n0 + r) * DM + kt + cg * 8,
                    Bs + (wave * 32 + it * 8) * BK);
            const int lr = m0 + r;
            const int xrow = ((lr >> 9) << 12) + ci * TC + (lr & (TC - 1));
            async16(Xb + (size_t)xrow * DM + kt + cg * 8,
                    As + (wave * 32 + it * 8) * BK);
        }
        __syncthreads();
#pragma unroll
        for (int ks = 0; ks < BK; ks += 32) {
            bf16x8 af[4], bfr[4];
#pragma unroll
            for (int i = 0; i < 4; i++) {
                const int r = wm + i * 16 + l16;
                const int ch = ((ks >> 3) + quad) ^ (r & 7);
                af[i] = *(const bf16x8*)(As + r * BK + ch * 8);
            }
#pragma unroll
            for (int j = 0; j < 4; j++) {
                const int r = wn + j * 16 + l16;
                const int ch = ((ks >> 3) + quad) ^ (r & 7);
                bfr[j] = *(const bf16x8*)(Bs + r * BK + ch * 8);
            }
#pragma unroll
            for (int i = 0; i < 4; i++)
#pragma unroll
                for (int j = 0; j < 4; j++)
                    acc[i][j] = __builtin_amdgcn_mfma_f32_16x16x32_bf16(af[i], bfr[j], acc[i][j], 0, 0, 0);
        }
    }

    // hoisted per-column params for w=3 (n depends only on j)
    float Aj[4], bdj[4];
    if (w == 3) {
#pragma unroll
        for (int j = 0; j < 4; j++) {
            int n = n0 + wn + j * 16 + l16;
            Aj[j] = __expf(A_log[n]);
            bdj[j] = b_delta[n];
        }
    }

    // epilogue: C/D layout col=lane&15, row=quad*4+reg (m89-verified)
#pragma unroll
    for (int i = 0; i < 4; i++) {
#pragma unroll
        for (int j = 0; j < 4; j++) {
            int n = n0 + wn + j * 16 + l16;
#pragma unroll
            for (int r = 0; r < 4; r++) {
                int m = m0 + wm + i * 16 + quad * 4 + r;
                float z = acc[i][j][r];
                float o;
                if (w == 0) {
                    o = z;                                    // raw
                } else if (w == 1) {
                    o = 1.f / (1.f + __expf(-z));             // sigmoid gate
                } else if (w == 2) {
                    o = 1.f + tanh_fast(z);                   // 1 + mod
                } else {
                    float v = z + bdj[j];                     // softplus, stable
                    float sp = fmaxf(v, 0.f) + __logf(1.f + __expf(-fabsf(v)));
                    o = 1.f - __expf(-Aj[j] * sp);            // 1 - decay
                }
                Op[(size_t)m * DN + n] = f2bf(o);
            }
        }
    }
}

// ---------------- output GEMM: out[m][dm] = sum_k Z[m][k]*W_out[dm][k], K=4096 ----------------
// ROUND-6 VERBATIM (at ~900 TF m97-structure plateau, FETCH ideal).
__global__ __launch_bounds__(256, 4) void gemm_out_kernel(
    const u16* __restrict__ Zb, const u16* __restrict__ Wob, float* __restrict__ Out)
{
    const int bid = blockIdx.x;              // 0..511
    const int xcd = bid & 7;
    const int g = bid >> 3;                  // 0..63
    const int n_idx = g & 7;
    const int m_idx = xcd * 8 + (g >> 3);    // 0..63
    const int n0 = n_idx * BN;
    const int m0 = m_idx * BM;

    alignas(16) __shared__ u16 As[BM * BK];
    alignas(16) __shared__ u16 Bs[BN * BK];

    const int tid = threadIdx.x;
    const int lane = tid & 63;
    const int wave = tid >> 6;
    const int wm = (wave >> 1) * 64;
    const int wn = (wave & 1) * 64;
    const int l16 = lane & 15;
    const int quad = lane >> 4;
    const int sr8 = lane >> 3;
    const int cl = lane & 7;

    const f32x4 z4 = {0.f, 0.f, 0.f, 0.f};
    f32x4 acc[4][4];
#pragma unroll
    for (int i = 0; i < 4; i++)
#pragma unroll
        for (int j = 0; j < 4; j++) acc[i][j] = z4;

    for (int kt = 0; kt < DN; kt += BK) {
        __syncthreads();
#pragma unroll
        for (int it = 0; it < 4; ++it) {
            const int r = wave * 32 + it * 8 + sr8;
            const int cg = cl ^ (r & 7);
            async16(Zb + (size_t)(m0 + r) * DN + kt + cg * 8,
                    As + (wave * 32 + it * 8) * BK);
            async16(Wob + (size_t)(n0 + r) * DN + kt + cg * 8,
                    Bs + (wave * 32 + it * 8) * BK);
        }
        __syncthreads();
#pragma unroll
        for (int ks = 0; ks < BK; ks += 32) {
            bf16x8 af[4], bfr[4];
#pragma unroll
            for (int i = 0; i < 4; i++) {
                const int r = wm + i * 16 + l16;
                const int ch = ((ks >> 3) + quad) ^ (r & 7);
                af[i] = *(const bf16x8*)(As + r * BK + ch * 8);
            }
#pragma unroll
            for (int j = 0; j < 4; j++) {
                const int r = wn + j * 16 + l16;
                const int ch = ((ks >> 3) + quad) ^ (r & 7);
                bfr[j] = *(const bf16x8*)(Bs + r * BK + ch * 8);
            }
#pragma unroll
            for (int i = 0; i < 4; i++)
#pragma unroll
                for (int j = 0; j < 4; j++)
                    acc[i][j] = __builtin_amdgcn_mfma_f32_16x16x32_bf16(af[i], bfr[j], acc[i][j], 0, 0, 0);
        }
    }

#pragma unroll
    for (int i = 0; i < 4; i++)
#pragma unroll
        for (int j = 0; j < 4; j++) {
            int n = n0 + wn + j * 16 + l16;
#pragma unroll
            for (int r = 0; r < 4; r++) {
                int m = m0 + wm + i * 16 + quad * 4 + r;
                Out[(size_t)m * DM + n] = acc[i][j][r];
            }
        }
}

// ---------------- single-pass hierarchical scan for one time chunk ----------------
// Block = (batch b, 32-neuron slice), 1024 threads = 32 tg x 32 neurons. Phase 1 computes
// AND REGISTER-HOLDS per-step d, u, y=mp*(1-sw)*gelu(raw), msw=mp*sw (64 VGPRs, unrolled);
// phase 2 is pure register math + Z stores -> activations read ONCE (42 vs 67 MB/chunk).
__global__ __launch_bounds__(1024) void scan_fused(
    const u16* __restrict__ omd_a, const u16* __restrict__ sig_a,
    const u16* __restrict__ raw_a, const u16* __restrict__ modp_a,
    float* __restrict__ state_cur, const float* __restrict__ sw_logit,
    u16* __restrict__ Z, float* __restrict__ fs_out, int ci_t)
{
    __shared__ float Ds[32][32];
    __shared__ float Ss[32][32];
    __shared__ float Is[32][32];

    const int tid = threadIdx.x;
    const int nl = tid & 31;
    const int tg = tid >> 5;
    const int bx = blockIdx.x;               // BB * (DN/32) = 256 blocks
    const int nsl = bx & 127;
    const int b = bx >> 7;
    const int n = nsl * 32 + nl;

    const size_t base = ((size_t)(b * TC + tg * SCH)) * DN + n;   // chunk-local rows

    const float sw = 1.f / (1.f + __expf(-sw_logit[n]));
    const float osw = 1.f - sw;

    float dv[SCH], uv[SCH], yv[SCH], mswv[SCH];

    // phase 1: sub-chunk summary, hold recurrence inputs in registers
    float D = 1.f, s = 0.f;
#pragma unroll
    for (int t = 0; t < SCH; t++) {
        size_t idx = base + (size_t)t * DN;
        float omd = bf2f(omd_a[idx]);
        float sg = bf2f(sig_a[idx]);
        float rw = bf2f(raw_a[idx]);
        float mp = bf2f(modp_a[idx]);
        float d = 1.f - omd;
        float u = omd * sg * tanh_fast(rw);
        float g2 = 0.5f * rw * (1.f + erf_fast(rw * 0.70710678f));  // exact gelu
        dv[t] = d; uv[t] = u;
        yv[t] = mp * osw * g2;
        mswv[t] = mp * sw;
        D *= d;
        s = d * s + u;
    }
    Ds[tg][nl] = D;
    Ss[tg][nl] = s;
    __syncthreads();

    // prefix combine: tg==0 threads (one per neuron) walk the 32 summaries
    if (tg == 0) {
        float si = state_cur[b * DN + n];
        Is[0][nl] = si;
        for (int c = 0; c < 31; c++) {
            si = Ds[c][nl] * si + Ss[c][nl];
            Is[c + 1][nl] = si;
        }
    }
    __syncthreads();

    // phase 2: register-only re-scan, emit Z
    float s2 = Is[tg][nl];
    const size_t gbase = ((size_t)(b * TT + ci_t * TC + tg * SCH)) * DN + n;
#pragma unroll
    for (int t = 0; t < SCH; t++) {
        s2 = dv[t] * s2 + uv[t];
        Z[gbase + (size_t)t * DN] = f2bf(yv[t] + mswv[t] * s2);
    }
    if (tg == 31) {
        state_cur[b * DN + n] = s2;                 // carry to next chunk
        if (ci_t == NTC - 1) fs_out[b * DN + n] = s2;  // final_state output
    }
}

// ---------------- host launcher ----------------
extern "C" void kernel_launch(void* const* d_in, const int* in_sizes, int n_in,
                              void* d_out, int out_size, void* d_ws, size_t ws_size,
                              hipStream_t stream)
{
    const float* x = (const float*)d_in[0];
    const float* state = (const float*)d_in[1];
    const float* W_main = (const float*)d_in[2];
    const float* W_gate = (const float*)d_in[3];
    const float* W_mod = (const float*)d_in[4];
    const float* W_out = (const float*)d_in[5];
    const float* W_delta = (const float*)d_in[6];
    const float* b_delta = (const float*)d_in[7];
    const float* A_log = (const float*)d_in[8];
    const float* sw_logit = (const float*)d_in[9];

    float* out = (float*)d_out;                       // [B,T,Dm] fp32
    float* fs_out = out + (size_t)MR * DM;            // final_state [B,Dn]

    const size_t NM = (size_t)MR * DN;
    u16* Zb = (u16*)d_ws;                             // 67.11 MB
    u16* raw_c = Zb + NM;                             // 4 x 8.39 MB
    u16* sig_c = raw_c + CN;
    u16* modp_c = sig_c + CN;
    u16* omd_c = modp_c + CN;
    u16* W4b = omd_c + CN;                            // 33.55 MB
    u16* xb = W4b + (size_t)4 * DN * DM;              // 16.78 MB
    u16* woutb = xb + (size_t)MR * DM;                // 8.39 MB
    float* state_cur = (float*)(woutb + (size_t)DM * DN); // 32 KB
    // total = 159,416,320 B  (< 160,202,752 proven available)

    // one fused conversion launch: x + 4 proj weights + W_out + state copy
    {
        const int total4 = (MR * DM) / 4 + 5 * ((DN * DM) / 4) + (BB * DN) / 4;
        cvt7_kernel<<<(total4 + 255) / 256, 256, 0, stream>>>(
            (const float4*)x, (const float4*)W_main, (const float4*)W_gate,
            (const float4*)W_mod, (const float4*)W_delta, (const float4*)W_out,
            (const float4*)state,
            (ushort4*)xb, (ushort4*)W4b, (ushort4*)woutb, (float4*)state_cur);
    }

    for (int ci = 0; ci < NTC; ci++) {
        gemm4_kernel<<<1024, 256, 0, stream>>>(xb, W4b, raw_c, sig_c, modp_c, omd_c,
                                               A_log, b_delta, ci);
        scan_fused<<<BB * (DN / 32), 1024, 0, stream>>>(omd_c, sig_c, raw_c, modp_c,
                                                        state_cur, sw_logit,
                                                        Zb, fs_out, ci);
    }

    gemm_out_kernel<<<512, 256, 0, stream>>>(Zb, woutb, out);
}